// Round 5
// baseline (95.713 us; speedup 1.0000x reference)
//
#include <hip/hip_runtime.h>

#define UNITS 256
#define IN_DIM 16
#define CH 2
#define R0C 64
#define R1C 8
#define R2C 2
#define NROWS 262144

#define NBLK 1024                    // 4096 waves, one 64-row chunk each
#define K2LOG2E 2.8853900817779268f  // 2*log2(e)

typedef float v2f __attribute__((ext_vector_type(2)));
typedef float v4f __attribute__((ext_vector_type(4)));

// ws: per-unit 24 floats: w[8][2]*2log2e (16), bl0,bl1 (*2log2e), m0,m1, gs, pad3
#define UPACK 24
#define WS_FLOATS (UNITS * UPACK)

__device__ __forceinline__ void compute_unit_params(
    int u, const float* __restrict__ core, const float* __restrict__ f0,
    const float* __restrict__ f2, const float* __restrict__ bias,
    const float* __restrict__ fac, float wout[16], float aux[5]) {
    float r0[R1C][R2C] = {};
    #pragma unroll 8
    for (int a = 0; a < R0C; ++a) {
        float f0v = f0[u * R0C + a];
        #pragma unroll
        for (int j = 0; j < R1C; ++j)
            #pragma unroll
            for (int n = 0; n < R2C; ++n)
                r0[j][n] += f0v * core[(a * R1C + j) * R2C + n];
    }
    #pragma unroll
    for (int j = 0; j < R1C; ++j) {
        float w0 = r0[j][0] * f2[0 * R2C + 0] + r0[j][1] * f2[0 * R2C + 1];
        float w1 = r0[j][0] * f2[1 * R2C + 0] + r0[j][1] * f2[1 * R2C + 1];
        wout[j * 2 + 0] = w0 * K2LOG2E;
        wout[j * 2 + 1] = w1 * K2LOG2E;
    }
    float fc0 = fac[u * CH + 0], fc1 = fac[u * CH + 1];
    aux[0] = bias[u * CH + 0] * K2LOG2E;
    aux[1] = bias[u * CH + 1] * K2LOG2E;
    aux[2] = -2.0f * fc0;
    aux[3] = -2.0f * fc1;
    aux[4] = fc0 + fc1;
}

__global__ void wprep_kernel(const float* __restrict__ core,
                             const float* __restrict__ f0,
                             const float* __restrict__ f2,
                             const float* __restrict__ bias,
                             const float* __restrict__ fac,
                             float* __restrict__ ws) {
    int u = threadIdx.x;  // 256 threads, 1 block
    float w[16], aux[5];
    compute_unit_params(u, core, f0, f2, bias, fac, w, aux);
    float* p = ws + u * UPACK;
    #pragma unroll
    for (int k = 0; k < 16; ++k) p[k] = w[k];
    #pragma unroll
    for (int k = 0; k < 5; ++k) p[16 + k] = aux[k];
    p[21] = 0.f; p[22] = 0.f; p[23] = 0.f;
}

template <bool USE_WS>
__global__ __launch_bounds__(256) void mdense_main(
    const float* __restrict__ x,      // [N][16]
    const float* __restrict__ f1,     // [16][8]
    const float* __restrict__ wsbuf,  // packed params (USE_WS)
    const float* __restrict__ core, const float* __restrict__ f0,
    const float* __restrict__ f2, const float* __restrict__ bias,
    const float* __restrict__ fac,
    float* __restrict__ out)          // [N][256]
{
    __shared__ float F1s[IN_DIM * R1C];  // 512 B
    const int tid = threadIdx.x;
    if (tid < 32)
        reinterpret_cast<float4*>(F1s)[tid] = reinterpret_cast<const float4*>(f1)[tid];
    __syncthreads();

    const int W = blockIdx.x * 4 + (tid >> 6);  // chunk id, 0..4095
    const int lane = tid & 63;
    const int u0 = lane * 4;  // this lane's 4 consecutive units

    // ---- per-lane params for 4 units ----
    v2f wv[4][R1C];     // weights (pre-scaled)
    v2f blv[4], mv[4];  // bias*2log2e, -2*fac
    float gs[4];        // fac0+fac1
    if (USE_WS) {
        #pragma unroll
        for (int q = 0; q < 4; ++q) {
            const float4* p4 = reinterpret_cast<const float4*>(wsbuf + (u0 + q) * UPACK);
            float4 w0 = p4[0], w1 = p4[1], w2 = p4[2], w3 = p4[3], a = p4[4];
            wv[q][0] = (v2f){w0.x, w0.y}; wv[q][1] = (v2f){w0.z, w0.w};
            wv[q][2] = (v2f){w1.x, w1.y}; wv[q][3] = (v2f){w1.z, w1.w};
            wv[q][4] = (v2f){w2.x, w2.y}; wv[q][5] = (v2f){w2.z, w2.w};
            wv[q][6] = (v2f){w3.x, w3.y}; wv[q][7] = (v2f){w3.z, w3.w};
            blv[q] = (v2f){a.x, a.y};
            mv[q]  = (v2f){a.z, a.w};
            gs[q] = wsbuf[(u0 + q) * UPACK + 20];
        }
    } else {
        for (int q = 0; q < 4; ++q) {
            float w[16], aux[5];
            compute_unit_params(u0 + q, core, f0, f2, bias, fac, w, aux);
            #pragma unroll
            for (int j = 0; j < R1C; ++j) wv[q][j] = (v2f){w[j * 2], w[j * 2 + 1]};
            blv[q] = (v2f){aux[0], aux[1]};
            mv[q]  = (v2f){aux[2], aux[3]};
            gs[q] = aux[4];
        }
    }

    // ---- load this lane's x row, compute its Y[8] ----
    const size_t rowbase = (size_t)W * 64;
    const float4* xp = reinterpret_cast<const float4*>(x + (rowbase + lane) * IN_DIM);
    float4 X0 = xp[0], X1 = xp[1], X2 = xp[2], X3 = xp[3];
    const float xs[16] = {X0.x, X0.y, X0.z, X0.w, X1.x, X1.y, X1.z, X1.w,
                          X2.x, X2.y, X2.z, X2.w, X3.x, X3.y, X3.z, X3.w};
    v2f Yv[4] = {(v2f){0.f, 0.f}, (v2f){0.f, 0.f}, (v2f){0.f, 0.f}, (v2f){0.f, 0.f}};
    #pragma unroll
    for (int i = 0; i < IN_DIM; ++i) {
        v2f xv = {xs[i], xs[i]};
        float4 ha = *reinterpret_cast<const float4*>(&F1s[i * R1C]);
        float4 hb = *reinterpret_cast<const float4*>(&F1s[i * R1C + 4]);
        Yv[0] += xv * (v2f){ha.x, ha.y};
        Yv[1] += xv * (v2f){ha.z, ha.w};
        Yv[2] += xv * (v2f){hb.x, hb.y};
        Yv[3] += xv * (v2f){hb.z, hb.w};
    }
    float yl[8] = {Yv[0][0], Yv[0][1], Yv[1][0], Yv[1][1],
                   Yv[2][0], Yv[2][1], Yv[3][0], Yv[3][1]};

    // ---- 64 rows: broadcast Y via readlane, 4 units/lane, plain float4 store ----
    float* obase = out + rowbase * UNITS;
    #pragma unroll 2
    for (int r = 0; r < 64; ++r) {
        float yr[8];
        #pragma unroll
        for (int j = 0; j < R1C; ++j)
            yr[j] = __int_as_float(
                __builtin_amdgcn_readlane(__float_as_int(yl[j]), r));

        v2f acc0 = blv[0], acc1 = blv[1], acc2 = blv[2], acc3 = blv[3];
        #pragma unroll
        for (int j = 0; j < R1C; ++j) {
            v2f ys = {yr[j], yr[j]};
            acc0 += ys * wv[0][j];
            acc1 += ys * wv[1][j];
            acc2 += ys * wv[2][j];
            acc3 += ys * wv[3][j];
        }
        v4f o;
        {
            float e0 = __builtin_amdgcn_exp2f(acc0[0]);
            float e1 = __builtin_amdgcn_exp2f(acc0[1]);
            float r0 = __builtin_amdgcn_rcpf(1.0f + e0);
            float r1 = __builtin_amdgcn_rcpf(1.0f + e1);
            o.x = __builtin_fmaf(mv[0][0], r0, __builtin_fmaf(mv[0][1], r1, gs[0]));
        }
        {
            float e0 = __builtin_amdgcn_exp2f(acc1[0]);
            float e1 = __builtin_amdgcn_exp2f(acc1[1]);
            float r0 = __builtin_amdgcn_rcpf(1.0f + e0);
            float r1 = __builtin_amdgcn_rcpf(1.0f + e1);
            o.y = __builtin_fmaf(mv[1][0], r0, __builtin_fmaf(mv[1][1], r1, gs[1]));
        }
        {
            float e0 = __builtin_amdgcn_exp2f(acc2[0]);
            float e1 = __builtin_amdgcn_exp2f(acc2[1]);
            float r0 = __builtin_amdgcn_rcpf(1.0f + e0);
            float r1 = __builtin_amdgcn_rcpf(1.0f + e1);
            o.z = __builtin_fmaf(mv[2][0], r0, __builtin_fmaf(mv[2][1], r1, gs[2]));
        }
        {
            float e0 = __builtin_amdgcn_exp2f(acc3[0]);
            float e1 = __builtin_amdgcn_exp2f(acc3[1]);
            float r0 = __builtin_amdgcn_rcpf(1.0f + e0);
            float r1 = __builtin_amdgcn_rcpf(1.0f + e1);
            o.w = __builtin_fmaf(mv[3][0], r0, __builtin_fmaf(mv[3][1], r1, gs[3]));
        }
        *(reinterpret_cast<v4f*>(obase + (size_t)r * UNITS) + lane) = o;
    }
}

extern "C" void kernel_launch(void* const* d_in, const int* in_sizes, int n_in,
                              void* d_out, int out_size, void* d_ws, size_t ws_size,
                              hipStream_t stream) {
    const float* x    = (const float*)d_in[0];
    const float* core = (const float*)d_in[1];
    const float* f0   = (const float*)d_in[2];
    const float* f1   = (const float*)d_in[3];
    const float* f2   = (const float*)d_in[4];
    const float* bias = (const float*)d_in[5];
    const float* fac  = (const float*)d_in[6];
    float* out = (float*)d_out;

    if (ws_size >= WS_FLOATS * sizeof(float)) {
        float* ws = (float*)d_ws;
        wprep_kernel<<<1, 256, 0, stream>>>(core, f0, f2, bias, fac, ws);
        mdense_main<true><<<NBLK, 256, 0, stream>>>(x, f1, ws, core, f0, f2,
                                                    bias, fac, out);
    } else {
        mdense_main<false><<<NBLK, 256, 0, stream>>>(x, f1, nullptr, core, f0,
                                                     f2, bias, fac, out);
    }
}

// Round 6
// 67.966 us; speedup vs baseline: 1.4082x; 1.4082x over previous
//
#include <hip/hip_runtime.h>

#define UNITS 256
#define IN_DIM 16
#define CH 2
#define R0C 64
#define R1C 8
#define R2C 2
#define NROWS 262144

#define NBLK 1024                    // 4096 waves, one 64-row chunk each
#define K2LOG2E 2.8853900817779268f  // 2*log2(e)

typedef float v2f __attribute__((ext_vector_type(2)));
typedef float v4f __attribute__((ext_vector_type(4)));

// ws: per-unit 24 floats: w[8][2]*2log2e (16), bl0,bl1 (*2log2e), m0,m1, gs, pad3
#define UPACK 24
#define WS_FLOATS (UNITS * UPACK)

__device__ __forceinline__ void compute_unit_params(
    int u, const float* __restrict__ core, const float* __restrict__ f0,
    const float* __restrict__ f2, const float* __restrict__ bias,
    const float* __restrict__ fac, float wout[16], float aux[5]) {
    float r0[R1C][R2C] = {};
    #pragma unroll 8
    for (int a = 0; a < R0C; ++a) {
        float f0v = f0[u * R0C + a];
        #pragma unroll
        for (int j = 0; j < R1C; ++j)
            #pragma unroll
            for (int n = 0; n < R2C; ++n)
                r0[j][n] += f0v * core[(a * R1C + j) * R2C + n];
    }
    #pragma unroll
    for (int j = 0; j < R1C; ++j) {
        float w0 = r0[j][0] * f2[0 * R2C + 0] + r0[j][1] * f2[0 * R2C + 1];
        float w1 = r0[j][0] * f2[1 * R2C + 0] + r0[j][1] * f2[1 * R2C + 1];
        wout[j * 2 + 0] = w0 * K2LOG2E;
        wout[j * 2 + 1] = w1 * K2LOG2E;
    }
    float fc0 = fac[u * CH + 0], fc1 = fac[u * CH + 1];
    aux[0] = bias[u * CH + 0] * K2LOG2E;
    aux[1] = bias[u * CH + 1] * K2LOG2E;
    aux[2] = -2.0f * fc0;
    aux[3] = -2.0f * fc1;
    aux[4] = fc0 + fc1;
}

__global__ void wprep_kernel(const float* __restrict__ core,
                             const float* __restrict__ f0,
                             const float* __restrict__ f2,
                             const float* __restrict__ bias,
                             const float* __restrict__ fac,
                             float* __restrict__ ws) {
    int u = threadIdx.x;  // 256 threads, 1 block
    float w[16], aux[5];
    compute_unit_params(u, core, f0, f2, bias, fac, w, aux);
    float* p = ws + u * UPACK;
    #pragma unroll
    for (int k = 0; k < 16; ++k) p[k] = w[k];
    #pragma unroll
    for (int k = 0; k < 5; ++k) p[16 + k] = aux[k];
    p[21] = 0.f; p[22] = 0.f; p[23] = 0.f;
}

template <bool USE_WS>
__global__ __launch_bounds__(256) void mdense_main(
    const float* __restrict__ x,      // [N][16]
    const float* __restrict__ f1,     // [16][8]
    const float* __restrict__ wsbuf,  // packed params (USE_WS)
    const float* __restrict__ core, const float* __restrict__ f0,
    const float* __restrict__ f2, const float* __restrict__ bias,
    const float* __restrict__ fac,
    float* __restrict__ out)          // [N][256]
{
    __shared__ float F1s[IN_DIM * R1C];  // 512 B
    const int tid = threadIdx.x;
    if (tid < 32)
        reinterpret_cast<float4*>(F1s)[tid] = reinterpret_cast<const float4*>(f1)[tid];
    __syncthreads();

    const int W = blockIdx.x * 4 + (tid >> 6);  // chunk id, 0..4095
    const int lane = tid & 63;
    const int u0 = lane * 4;  // this lane's 4 consecutive units

    // ---- per-lane params for 4 units ----
    v2f wv[4][R1C];     // weights (pre-scaled)
    v2f blv[4], mv[4];  // bias*2log2e, -2*fac
    float gs[4];        // fac0+fac1
    if (USE_WS) {
        #pragma unroll
        for (int q = 0; q < 4; ++q) {
            const float4* p4 = reinterpret_cast<const float4*>(wsbuf + (u0 + q) * UPACK);
            float4 w0 = p4[0], w1 = p4[1], w2 = p4[2], w3 = p4[3], a = p4[4];
            wv[q][0] = (v2f){w0.x, w0.y}; wv[q][1] = (v2f){w0.z, w0.w};
            wv[q][2] = (v2f){w1.x, w1.y}; wv[q][3] = (v2f){w1.z, w1.w};
            wv[q][4] = (v2f){w2.x, w2.y}; wv[q][5] = (v2f){w2.z, w2.w};
            wv[q][6] = (v2f){w3.x, w3.y}; wv[q][7] = (v2f){w3.z, w3.w};
            blv[q] = (v2f){a.x, a.y};
            mv[q]  = (v2f){a.z, a.w};
            gs[q] = wsbuf[(u0 + q) * UPACK + 20];
        }
    } else {
        for (int q = 0; q < 4; ++q) {
            float w[16], aux[5];
            compute_unit_params(u0 + q, core, f0, f2, bias, fac, w, aux);
            #pragma unroll
            for (int j = 0; j < R1C; ++j) wv[q][j] = (v2f){w[j * 2], w[j * 2 + 1]};
            blv[q] = (v2f){aux[0], aux[1]};
            mv[q]  = (v2f){aux[2], aux[3]};
            gs[q] = aux[4];
        }
    }

    // ---- load this lane's x row, compute its Y[8] ----
    const size_t rowbase = (size_t)W * 64;
    const float4* xp = reinterpret_cast<const float4*>(x + (rowbase + lane) * IN_DIM);
    float4 X0 = xp[0], X1 = xp[1], X2 = xp[2], X3 = xp[3];
    const float xs[16] = {X0.x, X0.y, X0.z, X0.w, X1.x, X1.y, X1.z, X1.w,
                          X2.x, X2.y, X2.z, X2.w, X3.x, X3.y, X3.z, X3.w};
    v2f Yv[4] = {(v2f){0.f, 0.f}, (v2f){0.f, 0.f}, (v2f){0.f, 0.f}, (v2f){0.f, 0.f}};
    #pragma unroll
    for (int i = 0; i < IN_DIM; ++i) {
        v2f xv = {xs[i], xs[i]};
        float4 ha = *reinterpret_cast<const float4*>(&F1s[i * R1C]);
        float4 hb = *reinterpret_cast<const float4*>(&F1s[i * R1C + 4]);
        Yv[0] += xv * (v2f){ha.x, ha.y};
        Yv[1] += xv * (v2f){ha.z, ha.w};
        Yv[2] += xv * (v2f){hb.x, hb.y};
        Yv[3] += xv * (v2f){hb.z, hb.w};
    }
    float yl[8] = {Yv[0][0], Yv[0][1], Yv[1][0], Yv[1][1],
                   Yv[2][0], Yv[2][1], Yv[3][0], Yv[3][1]};

    // ---- 64 rows, 4 at a time: 4 independent compute+store streams ----
    float* obase = out + rowbase * UNITS;
    for (int r4 = 0; r4 < 64; r4 += 4) {
        v4f ov[4];
        #pragma unroll
        for (int s = 0; s < 4; ++s) {
            const int r = r4 + s;
            float yr[8];
            #pragma unroll
            for (int j = 0; j < R1C; ++j)
                yr[j] = __int_as_float(
                    __builtin_amdgcn_readlane(__float_as_int(yl[j]), r));

            v2f acc0 = blv[0], acc1 = blv[1], acc2 = blv[2], acc3 = blv[3];
            #pragma unroll
            for (int j = 0; j < R1C; ++j) {
                v2f ys = {yr[j], yr[j]};
                acc0 += ys * wv[0][j];
                acc1 += ys * wv[1][j];
                acc2 += ys * wv[2][j];
                acc3 += ys * wv[3][j];
            }
            float e00 = __builtin_amdgcn_exp2f(acc0[0]);
            float e01 = __builtin_amdgcn_exp2f(acc0[1]);
            float e10 = __builtin_amdgcn_exp2f(acc1[0]);
            float e11 = __builtin_amdgcn_exp2f(acc1[1]);
            float e20 = __builtin_amdgcn_exp2f(acc2[0]);
            float e21 = __builtin_amdgcn_exp2f(acc2[1]);
            float e30 = __builtin_amdgcn_exp2f(acc3[0]);
            float e31 = __builtin_amdgcn_exp2f(acc3[1]);
            float r00 = __builtin_amdgcn_rcpf(1.0f + e00);
            float r01 = __builtin_amdgcn_rcpf(1.0f + e01);
            float r10 = __builtin_amdgcn_rcpf(1.0f + e10);
            float r11 = __builtin_amdgcn_rcpf(1.0f + e11);
            float r20 = __builtin_amdgcn_rcpf(1.0f + e20);
            float r21 = __builtin_amdgcn_rcpf(1.0f + e21);
            float r30 = __builtin_amdgcn_rcpf(1.0f + e30);
            float r31 = __builtin_amdgcn_rcpf(1.0f + e31);
            ov[s].x = __builtin_fmaf(mv[0][0], r00, __builtin_fmaf(mv[0][1], r01, gs[0]));
            ov[s].y = __builtin_fmaf(mv[1][0], r10, __builtin_fmaf(mv[1][1], r11, gs[1]));
            ov[s].z = __builtin_fmaf(mv[2][0], r20, __builtin_fmaf(mv[2][1], r21, gs[2]));
            ov[s].w = __builtin_fmaf(mv[3][0], r30, __builtin_fmaf(mv[3][1], r31, gs[3]));
        }
        #pragma unroll
        for (int s = 0; s < 4; ++s) {
            v4f* p4 = reinterpret_cast<v4f*>(obase + (size_t)(r4 + s) * UNITS) + lane;
            __builtin_nontemporal_store(ov[s], p4);
        }
    }
}

extern "C" void kernel_launch(void* const* d_in, const int* in_sizes, int n_in,
                              void* d_out, int out_size, void* d_ws, size_t ws_size,
                              hipStream_t stream) {
    const float* x    = (const float*)d_in[0];
    const float* core = (const float*)d_in[1];
    const float* f0   = (const float*)d_in[2];
    const float* f1   = (const float*)d_in[3];
    const float* f2   = (const float*)d_in[4];
    const float* bias = (const float*)d_in[5];
    const float* fac  = (const float*)d_in[6];
    float* out = (float*)d_out;

    if (ws_size >= WS_FLOATS * sizeof(float)) {
        float* ws = (float*)d_ws;
        wprep_kernel<<<1, 256, 0, stream>>>(core, f0, f2, bias, fac, ws);
        mdense_main<true><<<NBLK, 256, 0, stream>>>(x, f1, ws, core, f0, f2,
                                                    bias, fac, out);
    } else {
        mdense_main<false><<<NBLK, 256, 0, stream>>>(x, f1, nullptr, core, f0,
                                                     f2, bias, fac, out);
    }
}